// Round 1
// baseline (517.841 us; speedup 1.0000x reference)
//
#include <hip/hip_runtime.h>

// Output layout (all float32, concatenated flat in reference return order):
//   [0, 3V)                : verts_3d  (V,3)
//   [3V, 3V + nF)          : faces cast to float (F,3)
//   [3V + nF, ... + V*D)   : verts_features (V,D) pass-through

__global__ void verts3d_kernel(const float* __restrict__ logit,
                               const float* __restrict__ boundary,
                               float* __restrict__ out, int V) {
    int i = blockIdx.x * blockDim.x + threadIdx.x;
    if (i >= V) return;
    float x, y;
    if (i < 4) {
        x = boundary[2 * i];
        y = boundary[2 * i + 1];
    } else {
        float lx = logit[2 * i];
        float ly = logit[2 * i + 1];
        // sigmoid(x)*2 - 1
        x = 2.0f / (1.0f + expf(-lx)) - 1.0f;
        y = 2.0f / (1.0f + expf(-ly)) - 1.0f;
    }
    out[3 * i + 0] = x;
    out[3 * i + 1] = y;
    out[3 * i + 2] = 1.0f;
}

__global__ void faces_cast_kernel(const int* __restrict__ faces,
                                  float* __restrict__ out, int n) {
    int i = blockIdx.x * blockDim.x + threadIdx.x;
    if (i < n) out[i] = (float)faces[i];
}

extern "C" void kernel_launch(void* const* d_in, const int* in_sizes, int n_in,
                              void* d_out, int out_size, void* d_ws, size_t ws_size,
                              hipStream_t stream) {
    const float* verts_logit    = (const float*)d_in[0];
    const float* verts_features = (const float*)d_in[1];
    const float* boundary       = (const float*)d_in[2];
    const int*   faces          = (const int*)d_in[3];

    const int V  = in_sizes[0] / 2;         // 500000
    const int nF = in_sizes[3];             // F*3 flat elems
    const long long featElems = (long long)in_sizes[1];  // V*D

    float* out = (float*)d_out;
    float* out_verts3d  = out;
    float* out_faces    = out + (long long)3 * V;
    float* out_features = out_faces + nF;

    // 1) verts_3d
    {
        int threads = 256;
        int blocks = (V + threads - 1) / threads;
        verts3d_kernel<<<blocks, threads, 0, stream>>>(verts_logit, boundary,
                                                       out_verts3d, V);
    }
    // 2) faces int -> float cast-copy
    {
        int threads = 256;
        int blocks = (nF + threads - 1) / threads;
        faces_cast_kernel<<<blocks, threads, 0, stream>>>(faces, out_faces, nF);
    }
    // 3) features pass-through: tuned D2D copy (graph-capture safe, async on stream)
    hipMemcpyAsync(out_features, verts_features,
                   (size_t)featElems * sizeof(float),
                   hipMemcpyDeviceToDevice, stream);
}

// Round 2
// 456.877 us; speedup vs baseline: 1.1334x; 1.1334x over previous
//
#include <hip/hip_runtime.h>

// Output layout (all float32, concatenated flat in reference return order):
//   [0, 3V)              : verts_3d  (V,3)  = sigmoid(logit)*2-1 (rows 0..3 = boundary), col2 = 1
//   [3V, 3V+nF)          : faces cast int->float (F,3)
//   [3V+nF, +V*D)        : verts_features pass-through
//
// One fused kernel: every thread participates in the grid-stride float4 copy of
// the dominant features block; the first W1+W2+1 threads additionally handle the
// verts_3d compute and the faces cast (disjoint output ranges, no ordering needed).

typedef float f32x4 __attribute__((ext_vector_type(4)));
typedef int   i32x4 __attribute__((ext_vector_type(4)));

__global__ __launch_bounds__(256) void fused_screen_tri(
    const float* __restrict__ logit,
    const float* __restrict__ feats,
    const float* __restrict__ boundary,
    const int*  __restrict__ faces,
    float* __restrict__ out,
    int V, int nF, long long nFeat)
{
    const long long gid      = (long long)blockIdx.x * 256 + threadIdx.x;
    const long long nthreads = (long long)gridDim.x * 256;

    float* outV = out;                 // 3V floats
    float* outF = out + (long long)3 * V;   // nF floats
    float* outX = outF + nF;           // nFeat floats

    const long long W1  = (V + 3) >> 2;    // verts groups of 4
    const long long n4f = nF >> 2;         // faces float4 groups

    if (gid < W1) {
        const int base = (int)gid << 2;
        if (gid == 0) {
            // group 0 holds exactly the 4 boundary-pinned rows
            for (int v = 0; v < 4 && v < V; ++v) {
                outV[3 * v + 0] = boundary[2 * v];
                outV[3 * v + 1] = boundary[2 * v + 1];
                outV[3 * v + 2] = 1.0f;
            }
        } else if (base + 4 <= V) {
            // vectorized: 8 floats in (2x float4), 12 floats out (3x float4)
            f32x4 l0 = *(const f32x4*)(logit + 2 * base);
            f32x4 l1 = *(const f32x4*)(logit + 2 * base + 4);
            float xs[4] = { l0.x, l0.z, l1.x, l1.z };
            float ys[4] = { l0.y, l0.w, l1.y, l1.w };
            float o[12] __attribute__((aligned(16)));
            #pragma unroll
            for (int k = 0; k < 4; ++k) {
                o[3 * k + 0] = 2.0f / (1.0f + expf(-xs[k])) - 1.0f;
                o[3 * k + 1] = 2.0f / (1.0f + expf(-ys[k])) - 1.0f;
                o[3 * k + 2] = 1.0f;
            }
            f32x4* dp = (f32x4*)(outV + 3 * base);   // 3*base % 4 == 0 -> 16B aligned
            dp[0] = *(const f32x4*)&o[0];
            dp[1] = *(const f32x4*)&o[4];
            dp[2] = *(const f32x4*)&o[8];
        } else {
            for (int v = base; v < V; ++v) {
                float sx = 2.0f / (1.0f + expf(-logit[2 * v])) - 1.0f;
                float sy = 2.0f / (1.0f + expf(-logit[2 * v + 1])) - 1.0f;
                outV[3 * v + 0] = sx;
                outV[3 * v + 1] = sy;
                outV[3 * v + 2] = 1.0f;
            }
        }
    } else if (gid < W1 + n4f + 1) {
        const long long j = gid - W1;
        if (j < n4f) {
            i32x4 fi = *(const i32x4*)(faces + 4 * j);
            f32x4 fo;
            fo.x = (float)fi.x; fo.y = (float)fi.y;
            fo.z = (float)fi.z; fo.w = (float)fi.w;
            *(f32x4*)(outF + 4 * j) = fo;   // 3V % 4 == 0 -> aligned
        } else {
            for (int t = (int)(n4f << 2); t < nF; ++t) outF[t] = (float)faces[t];
        }
    }

    // ---- features copy: ALL threads, grid-stride float4, dst-aligned ----
    int peel = (int)(((long long)3 * V + nF) & 3);
    peel = (4 - peel) & 3;                       // scalar head so dst is 16B-aligned
    if (peel > nFeat) peel = (int)nFeat;
    if (gid < peel) outX[gid] = feats[gid];

    const float* s = feats + peel;               // may be only 4B-aligned
    float*       d = outX + peel;                // 16B-aligned by construction
    const long long m  = nFeat - peel;
    const long long m4 = m >> 2;
    for (long long i = gid; i < m4; i += nthreads) {
        f32x4 v;
        __builtin_memcpy(&v, s + 4 * i, sizeof(v));   // alignment-safe wide load
        *(f32x4*)(d + 4 * i) = v;
    }
    for (long long i = (m4 << 2) + gid; i < m; i += nthreads) d[i] = s[i];
}

extern "C" void kernel_launch(void* const* d_in, const int* in_sizes, int n_in,
                              void* d_out, int out_size, void* d_ws, size_t ws_size,
                              hipStream_t stream) {
    const float* verts_logit    = (const float*)d_in[0];
    const float* verts_features = (const float*)d_in[1];
    const float* boundary       = (const float*)d_in[2];
    const int*   faces          = (const int*)d_in[3];

    const int V  = in_sizes[0] / 2;             // 500000
    const int nF = in_sizes[3];                 // F*3 flat elems
    const long long nFeat = (long long)in_sizes[1];  // V*D

    long long W1  = (V + 3) / 4;
    long long n4f = nF / 4;
    long long smallThreads = W1 + n4f + 1;
    int blocksSmall = (int)((smallThreads + 255) / 256);
    int blocks = 8192;                           // 32 blocks/CU worth of copy waves
    if (blocksSmall > blocks) blocks = blocksSmall;

    fused_screen_tri<<<blocks, 256, 0, stream>>>(
        verts_logit, verts_features, boundary, faces,
        (float*)d_out, V, nF, nFeat);
}